// Round 1
// 184.817 us; speedup vs baseline: 1.0042x; 1.0042x over previous
//
#include <hip/hip_runtime.h>
#include <cmath>

// ---------------------------------------------------------------------------
// JPEG compress (YCbCr + 2x2 chroma pool + 8x8 DCT + quantize/round).
//
// Numerics contract (VERIFIED r4/r6, absmax 0.0): f32 end-to-end, every
// accumulation step is mul-then-add with TWO roundings (numpy baseline-SIMD,
// no FMA). __f*_rn builtins are contractible in HIP -- all value-path
// mul/add/sub are inline-asm v_mul_f32 / v_add_f32 / v_sub_f32 (asm boundary
// blocks FMA formation). fdiv/rint stay as builtins (verified r4/r6).
//
// Recipe per output (DO NOT CHANGE):
//   t_c   = rn(x_c * 255)
//   y     = chain c=R,G,B: a = rn(a + rn(t_c*k_c));  X = rn(a - 128)
//   cb/cr = same chain + 128; pool ((p00+p01)+p10)+p11 * 0.25; - 128
//   dct_i = 64-step chain j=(x,y) row-major from 0: a = rn(a + rn(T_ij*X_j))
//   outv  = rintf( rn( rn(sc_i * dct_i) / q_i ) )
//
// R7->R8: force T[64] RESIDENT in VGPRs. r7's VGPR_Count=52 proved the
// occupancy-driven scheduler sank/remat'd the per-lane DCT-row loads INTO the
// phase-2 loop (re-fetching ~64 T values from L2 per 2-block iteration:
// ~1.6 GB L2 traffic + address VALU -> VALUBusy 70% with 30% stall).
// Fix: empty inline-asm pins after the T loads (non-rematerializable,
// multi-use -> cannot sink; ~85 live regs < 128 budget at launch_bounds
// (256,4) -> no spill). Also: emit uses 32-bit offsets (drop 64-bit addr
// chains per store). Value-path math is byte-identical to r7.
// ---------------------------------------------------------------------------

namespace jc {

constexpr double c1 = 0.98078528040323044912618223613424;  // cos(1*pi/16)
constexpr double c2 = 0.92387953251128675612818318939679;  // cos(2*pi/16)
constexpr double c3 = 0.83146961230254523707878837761791;  // cos(3*pi/16)
constexpr double c4 = 0.70710678118654752440084436210485;  // cos(4*pi/16)
constexpr double c5 = 0.55557023301960222474283081394853;  // cos(5*pi/16)
constexpr double c6 = 0.38268343236508977172845998403040;  // cos(6*pi/16)
constexpr double c7 = 0.19509032201612826784828486847702;  // cos(7*pi/16)
constexpr double alpha0 = 0.70710678118654746171979706919384;  // 1.0/np.sqrt(2)

struct Tab {
  float tt[4096];  // TRANSPOSED: tt[j*64+i] = f32(CX[x][u]*CX[y][v]), j=(x,y), i=(u,v)
  float sc[64];    // f32(f64(alpha_u*alpha_v)*0.25)
  float yq[64];
  float cq[64];
  constexpr Tab() : tt(), sc(), yq(), cq() {
    const double CX[8][8] = {  // CX[x][u] = cos((2x+1)u*pi/16)
      {1.0,  c1,  c2,  c3,  c4,  c5,  c6,  c7},
      {1.0,  c3,  c6, -c7, -c4, -c1, -c2, -c5},
      {1.0,  c5, -c6, -c1, -c4,  c7,  c2,  c3},
      {1.0,  c7, -c2, -c5,  c4,  c3, -c6, -c1},
      {1.0, -c7, -c2,  c5,  c4, -c3, -c6,  c1},
      {1.0, -c5, -c6,  c1, -c4, -c7,  c2, -c3},
      {1.0, -c3,  c6,  c7, -c4,  c1, -c2,  c5},
      {1.0, -c1,  c2, -c3,  c4, -c5,  c6, -c7}};
    for (int i = 0; i < 64; ++i) {
      const int u = i >> 3, v = i & 7;
      for (int j = 0; j < 64; ++j) {
        const int x = j >> 3, y = j & 7;
        tt[j * 64 + i] = (float)(CX[x][u] * CX[y][v]);
      }
      const double au = (u == 0) ? alpha0 : 1.0;
      const double av = (v == 0) ? alpha0 : 1.0;
      sc[i] = (float)((au * av) * 0.25);
    }
    const int YT[64] = {
      16, 11, 10, 16, 24, 40, 51, 61,
      12, 12, 14, 19, 26, 58, 60, 55,
      14, 13, 16, 24, 40, 57, 69, 56,
      14, 17, 22, 29, 51, 87, 80, 62,
      18, 22, 37, 56, 68, 109, 103, 77,
      24, 35, 55, 64, 81, 104, 113, 92,
      49, 64, 78, 87, 103, 121, 120, 101,
      72, 92, 95, 98, 112, 100, 103, 99};
    const int CT[64] = {
      17, 18, 24, 47, 99, 99, 99, 99,
      18, 21, 26, 66, 99, 99, 99, 99,
      24, 26, 56, 99, 99, 99, 99, 99,
      47, 66, 99, 99, 99, 99, 99, 99,
      99, 99, 99, 99, 99, 99, 99, 99,
      99, 99, 99, 99, 99, 99, 99, 99,
      99, 99, 99, 99, 99, 99, 99, 99,
      99, 99, 99, 99, 99, 99, 99, 99};
    for (int i = 0; i < 64; ++i) {
      yq[i] = (float)YT[i];
      cq[i] = (float)CT[i];
    }
  }
};

__device__ constexpr Tab TT;

}  // namespace jc

// ---- contraction-proof f32 ops (asm boundary blocks FMA formation) ----
__device__ __forceinline__ float vmul(float a, float b) {
  float r; asm("v_mul_f32 %0, %1, %2" : "=v"(r) : "v"(a), "v"(b)); return r;
}
__device__ __forceinline__ float vadd(float a, float b) {
  float r; asm("v_add_f32 %0, %1, %2" : "=v"(r) : "v"(a), "v"(b)); return r;
}
__device__ __forceinline__ float vsubf(float a, float b) {  // a - b
  float r; asm("v_sub_f32 %0, %1, %2" : "=v"(r) : "v"(a), "v"(b)); return r;
}

// chroma chain from pre-scaled t values (tR=rn(R*255) etc.), + 128 shift
__device__ __forceinline__ float chro_t(float tR, float tG, float tB,
                                        float kR, float kG, float kB) {
  float a = vmul(tR, kR);
  a = vadd(a, vmul(tG, kG));
  a = vadd(a, vmul(tB, kB));
  return vadd(a, 128.0f);
}

// grid: 2048 workgroups x 256 threads (4 waves). wg = 64x64-px region of one
// batch image: 64 Y blocks + 16 Cb + 16 Cr blocks, all from one pixel read.
__global__ __launch_bounds__(256, 4) void jpeg_kernel(const float* __restrict__ img,
                                                      float* __restrict__ out) {
  __shared__ float Xs[96][68];  // rows: 0..63 Y, 64..79 Cb, 80..95 Cr; stride 272B (16B-aligned)

  const int wid = blockIdx.x;
  const int t = threadIdx.x;
  const int b = wid >> 6;   // batch 0..31
  const int r = wid & 63;   // region 0..63 (8x8 grid of 64x64-px regions)

  // ================= phase 1: merged staging =================
  {
    const int yb = t & 63;   // Y block 0..63 within region
    const int q = t >> 6;    // row-pair 0..3 within the Y block
    const int by = yb >> 3, bx = yb & 7;
    const int prow = (r >> 3) * 64 + by * 8 + 2 * q;  // global pixel row (top of pair)
    const int pcol = (r & 7) * 64 + bx * 8;
    const float* rp = img + (size_t)b * 786432 + (size_t)prow * 512 + pcol;

    float tv[3][2][8];  // rn(px*255): channel, row-in-pair, col
#pragma unroll
    for (int c = 0; c < 3; ++c) {
#pragma unroll
      for (int rr = 0; rr < 2; ++rr) {
        const float* p0 = rp + c * 262144 + rr * 512;
        const float4 va = *(const float4*)(p0);
        const float4 vb = *(const float4*)(p0 + 4);
        tv[c][rr][0] = vmul(va.x, 255.0f);
        tv[c][rr][1] = vmul(va.y, 255.0f);
        tv[c][rr][2] = vmul(va.z, 255.0f);
        tv[c][rr][3] = vmul(va.w, 255.0f);
        tv[c][rr][4] = vmul(vb.x, 255.0f);
        tv[c][rr][5] = vmul(vb.y, 255.0f);
        tv[c][rr][6] = vmul(vb.z, 255.0f);
        tv[c][rr][7] = vmul(vb.w, 255.0f);
      }
    }
    // --- Y: 16 values -> Xs[yb][16q .. 16q+15] (j = (2q+rr)*8 + y) ---
#pragma unroll
    for (int rr = 0; rr < 2; ++rr) {
#pragma unroll
      for (int y = 0; y < 8; ++y) {
        float a = vmul(tv[0][rr][y], 0.299f);
        a = vadd(a, vmul(tv[1][rr][y], 0.587f));
        a = vadd(a, vmul(tv[2][rr][y], 0.114f));
        Xs[yb][16 * q + rr * 8 + y] = vsubf(a, 128.0f);
      }
    }
    // --- chroma: this thread owns chroma row lcr, cols 4bx..4bx+3 ---
    const int lcr = 4 * by + q;  // 0..31 within region
#pragma unroll
    for (int pc = 0; pc < 4; ++pc) {
      const int lcc = 4 * bx + pc;
      const int crow = 64 + ((lcr >> 3) * 4 + (lcc >> 3));  // Cb block row in Xs
      const int cell = (lcr & 7) * 8 + (lcc & 7);
      const int e = 2 * pc, o = 2 * pc + 1;
      // Cb
      {
        const float p00 = chro_t(tv[0][0][e], tv[1][0][e], tv[2][0][e], -0.168736f, -0.331264f, 0.5f);
        const float p01 = chro_t(tv[0][0][o], tv[1][0][o], tv[2][0][o], -0.168736f, -0.331264f, 0.5f);
        const float p10 = chro_t(tv[0][1][e], tv[1][1][e], tv[2][1][e], -0.168736f, -0.331264f, 0.5f);
        const float p11 = chro_t(tv[0][1][o], tv[1][1][o], tv[2][1][o], -0.168736f, -0.331264f, 0.5f);
        const float s = vadd(vadd(vadd(p00, p01), p10), p11);
        Xs[crow][cell] = vsubf(vmul(s, 0.25f), 128.0f);
      }
      // Cr
      {
        const float p00 = chro_t(tv[0][0][e], tv[1][0][e], tv[2][0][e], 0.5f, -0.418688f, -0.081312f);
        const float p01 = chro_t(tv[0][0][o], tv[1][0][o], tv[2][0][o], 0.5f, -0.418688f, -0.081312f);
        const float p10 = chro_t(tv[0][1][e], tv[1][1][e], tv[2][1][e], 0.5f, -0.418688f, -0.081312f);
        const float p11 = chro_t(tv[0][1][o], tv[1][1][o], tv[2][1][o], 0.5f, -0.418688f, -0.081312f);
        const float s = vadd(vadd(vadd(p00, p01), p10), p11);
        Xs[crow + 16][cell] = vsubf(vmul(s, 0.25f), 128.0f);
      }
    }
  }

  // --- per-lane DCT row into VGPRs (global loads overlap staging/barrier) ---
  const int w = t >> 6;     // wave 0..3
  const int lane = t & 63;  // output index i
  float T[64];
#pragma unroll
  for (int j = 0; j < 64; ++j) T[j] = jc::TT.tt[j * 64 + lane];
  // R8: pin every T[j] into a live VGPR. Empty asm is non-rematerializable
  // and multi-use -> MachineSinking/remat CANNOT push the loads into the
  // phase-2 loop (r7: VGPR_Count=52 proved it did exactly that).
#pragma unroll
  for (int j = 0; j < 64; ++j) asm("" : "+v"(T[j]));
  const float scv = jc::TT.sc[lane];
  const float yqv = jc::TT.yq[lane];
  const float cqv = jc::TT.cq[lane];

  __syncthreads();

  // ================= phase 2: DCT + quantize =================
  // wave w handles blocks w*24 .. w*24+23 (2-block interleave for ILP)
  const int ybase = b * 4096 + (r >> 3) * 512 + (r & 7) * 8;  // + by*64 + bx
  const int cbase = b * 1024 + (r >> 3) * 128 + (r & 7) * 4;  // + cy*32 + cx

  auto emit = [&](int blk, float acc) {
    float qv;
    unsigned off;  // 32-bit: max index ~12.58M << 2^31; kills 64-bit addr chains
    if (blk < 64) {
      qv = yqv;
      off = (unsigned)((ybase + (blk >> 3) * 64 + (blk & 7)) << 6);
    } else {
      qv = cqv;
      const int cc = blk & 15;
      off = 8388608u + (blk >= 80 ? 2097152u : 0u) +
            (unsigned)((cbase + (cc >> 2) * 32 + (cc & 3)) << 6);
    }
    out[off + (unsigned)lane] = rintf(__fdiv_rn(vmul(scv, acc), qv));
  };

  for (int n = 0; n < 24; n += 2) {
    const int bA = w * 24 + n;
    const int bB = bA + 1;
    float a0 = 0.0f, a1 = 0.0f;
#pragma unroll
    for (int j4 = 0; j4 < 16; ++j4) {
      const float4 xA = *(const float4*)&Xs[bA][j4 * 4];  // broadcast (uniform addr)
      const float4 xB = *(const float4*)&Xs[bB][j4 * 4];
      a0 = vadd(a0, vmul(T[4 * j4 + 0], xA.x));
      a1 = vadd(a1, vmul(T[4 * j4 + 0], xB.x));
      a0 = vadd(a0, vmul(T[4 * j4 + 1], xA.y));
      a1 = vadd(a1, vmul(T[4 * j4 + 1], xB.y));
      a0 = vadd(a0, vmul(T[4 * j4 + 2], xA.z));
      a1 = vadd(a1, vmul(T[4 * j4 + 2], xB.z));
      a0 = vadd(a0, vmul(T[4 * j4 + 3], xA.w));
      a1 = vadd(a1, vmul(T[4 * j4 + 3], xB.w));
    }
    emit(bA, a0);
    emit(bB, a1);
  }
}

extern "C" void kernel_launch(void* const* d_in, const int* in_sizes, int n_in,
                              void* d_out, int out_size, void* d_ws, size_t ws_size,
                              hipStream_t stream) {
  (void)in_sizes; (void)n_in; (void)d_ws; (void)ws_size; (void)out_size;
  const float* img = (const float*)d_in[0];
  float* out = (float*)d_out;
  jpeg_kernel<<<dim3(2048), dim3(256), 0, stream>>>(img, out);
}